// Round 8
// baseline (208.017 us; speedup 1.0000x reference)
//
#include <hip/hip_runtime.h>
#include <hip/hip_fp16.h>

typedef __attribute__((ext_vector_type(8))) _Float16 f16x8;
typedef __attribute__((ext_vector_type(4))) float f32x4;
typedef unsigned long long u64;

__device__ __forceinline__ void gload_lds16(const _Float16* g, _Float16* l) {
  __builtin_amdgcn_global_load_lds((const __attribute__((address_space(1))) void*)g,
                                   (__attribute__((address_space(3))) void*)l, 16, 0, 0);
}

// ---- prep: cvt q,v (y<16) + transpose 4 weights (y=16..19) + pack v_mask bits (y=20) ----
__global__ __launch_bounds__(256) void prep_kernel(
    const float* __restrict__ q, const float* __restrict__ v,
    const float* __restrict__ W0, const float* __restrict__ W1,
    const float* __restrict__ W2, const float* __restrict__ W3,
    const int* __restrict__ v_mask,
    _Float16* __restrict__ q16, _Float16* __restrict__ v16,
    _Float16* __restrict__ T0, _Float16* __restrict__ T1,
    _Float16* __restrict__ T2, _Float16* __restrict__ T3,
    u64* __restrict__ mask_bits) {
  __shared__ float tile[64 * 65];
  int tid = threadIdx.x, ybl = blockIdx.y;
  if (ybl < 16) {
    int i = (ybl * 256 + blockIdx.x) * 256 + tid;
    float4 fq = ((const float4*)q)[i];
    float4 fv = ((const float4*)v)[i];
    union { _Float16 h[4]; uint2 u; } oq, ov;
    oq.h[0] = (_Float16)fq.x; oq.h[1] = (_Float16)fq.y;
    oq.h[2] = (_Float16)fq.z; oq.h[3] = (_Float16)fq.w;
    ov.h[0] = (_Float16)fv.x; ov.h[1] = (_Float16)fv.y;
    ov.h[2] = (_Float16)fv.z; ov.h[3] = (_Float16)fv.w;
    *(uint2*)&q16[4 * (size_t)i] = oq.u;
    *(uint2*)&v16[4 * (size_t)i] = ov.u;
    return;
  }
  if (ybl == 20) {
    if (blockIdx.x == 0 && tid < 64) {
      int base = tid * 64;  // tid = b*16+kb -> keys [b*1024+kb*64, +64)
      u64 m = 0;
      for (int k = 0; k < 64; k++)
        m |= ((u64)(v_mask[base + k] != 0)) << k;
      mask_bits[tid] = m;
    }
    return;
  }
  int z = ybl - 16;
  const float* W = (z == 0) ? W0 : (z == 1) ? W1 : (z == 2) ? W2 : W3;
  _Float16* T = (z == 0) ? T0 : (z == 1) ? T1 : (z == 2) ? T2 : T3;
  int bx = (blockIdx.x & 15) * 64, by = (blockIdx.x >> 4) * 64;
  for (int it = 0; it < 4; it++) {
    int lin = it * 256 + tid;
    int r = lin >> 4, q4 = (lin & 15) * 4;
    float4 f = *(const float4*)&W[(size_t)(by + r) * 1024 + bx + q4];
    tile[r * 65 + q4 + 0] = f.x;
    tile[r * 65 + q4 + 1] = f.y;
    tile[r * 65 + q4 + 2] = f.z;
    tile[r * 65 + q4 + 3] = f.w;
  }
  __syncthreads();
  for (int it = 0; it < 2; it++) {
    int lin = it * 256 + tid;
    int orow = lin >> 3, seg = (lin & 7) * 8;
    union { uint4 u; _Float16 h[8]; } o;
    for (int e = 0; e < 8; e++) o.h[e] = (_Float16)tile[(seg + e) * 65 + orow];
    *(uint4*)&T[(size_t)(bx + orow) * 1024 + by + seg] = o.u;
  }
}

// ---- QKV GEMM: 128x128, BK=32, TRIPLE-buffer + counted vmcnt + raw s_barrier (T4) ------
__global__ __launch_bounds__(256, 3) void gemm_qkv_kernel(
    const _Float16* __restrict__ q16, const _Float16* __restrict__ v16,
    const _Float16* __restrict__ WqT, const _Float16* __restrict__ WkT,
    const _Float16* __restrict__ WvT,
    const float* __restrict__ bq, const float* __restrict__ bk, const float* __restrict__ bv,
    _Float16* __restrict__ Q16, _Float16* __restrict__ K16, _Float16* __restrict__ VT16) {
  int ord = blockIdx.x + (blockIdx.y << 3) + (blockIdx.z << 8);
  int wgid = (ord & 7) * 96 + (ord >> 3);   // 768 blocks, bijective
  int z = wgid >> 8;
  int rem = wgid & 255;
  int m0 = (rem >> 3) * 128, n0 = (rem & 7) * 128;

  const _Float16* A = (z == 0) ? q16 : v16;
  const _Float16* BT = (z == 0) ? WqT : ((z == 1) ? WkT : WvT);
  const float* bias = (z == 0) ? bq : ((z == 1) ? bk : bv);
  const int K = 1024;

  __shared__ _Float16 Alds[3][128 * 32];
  __shared__ _Float16 Blds[3][128 * 32];
  int tid = threadIdx.x, lane = tid & 63, w = tid >> 6;
  int c = lane & 15, g = lane >> 4;
  int wm = (w & 1) * 64, wn = (w >> 1) * 64;
  int rr = lane >> 2;
  int su = ((lane & 3) ^ (rr & 3)) * 8;

  const _Float16* gA[2]; const _Float16* gB[2]; int lo[2];
  for (int p = 0; p < 2; p++) {
    int row = w * 32 + p * 16 + rr;
    gA[p] = &A[(size_t)(m0 + row) * K + su];
    gB[p] = &BT[(size_t)(n0 + row) * K + su];
    lo[p] = (w * 32 + p * 16) * 32;
  }

  f32x4 acc[4][4];
  for (int i = 0; i < 4; i++)
    for (int j = 0; j < 4; j++)
      acc[i][j] = (f32x4){0.f, 0.f, 0.f, 0.f};

  // prologue: stage tiles 0 and 1 (issue order matters for vmcnt counting)
  for (int t = 0; t < 2; t++)
    for (int p = 0; p < 2; p++) {
      gload_lds16(gA[p] + t * 32, &Alds[t][lo[p]]);
      gload_lds16(gB[p] + t * 32, &Blds[t][lo[p]]);
    }

  int xa = (c & 3) << 4;
  int cur = 0;
  for (int kt = 0; kt < 32; kt++) {
    // drain tile-kt's 4 loads; keep tile-(kt+1)'s 4 in flight (never vmcnt(0) mid-loop)
    if (kt < 31) { asm volatile("s_waitcnt vmcnt(4)" ::: "memory"); }
    else         { asm volatile("s_waitcnt vmcnt(0)" ::: "memory"); }
    __builtin_amdgcn_s_barrier();
    __builtin_amdgcn_sched_barrier(0);
    if (kt + 2 < 32) {
      int s2 = cur + 2; if (s2 >= 3) s2 -= 3;
      for (int p = 0; p < 2; p++) {
        gload_lds16(gA[p] + (kt + 2) * 32, &Alds[s2][lo[p]]);
        gload_lds16(gB[p] + (kt + 2) * 32, &Blds[s2][lo[p]]);
      }
    }
    const char* ab = (const char*)&Alds[cur][0];
    const char* bb = (const char*)&Blds[cur][0];
    f16x8 af[4], bf[4];
    for (int i = 0; i < 4; i++)
      af[i] = *(const f16x8*)(ab + (wm + i * 16 + c) * 64 + ((g * 16) ^ xa));
    for (int j = 0; j < 4; j++)
      bf[j] = *(const f16x8*)(bb + (wn + j * 16 + c) * 64 + ((g * 16) ^ xa));
    for (int i = 0; i < 4; i++)
      for (int j = 0; j < 4; j++)
        acc[i][j] = __builtin_amdgcn_mfma_f32_16x16x32_f16(af[i], bf[j], acc[i][j], 0, 0, 0);
    cur = (cur == 2) ? 0 : cur + 1;
  }

  if (z < 2) {
    _Float16* C = (z == 0) ? Q16 : K16;
    for (int j = 0; j < 4; j++) {
      float bv_ = bias[n0 + wn + j * 16 + c];
      for (int i = 0; i < 4; i++) {
        int r = m0 + wm + i * 16 + g * 4;
        int cc = n0 + wn + j * 16 + c;
        for (int e = 0; e < 4; e++)
          C[(size_t)(r + e) * 1024 + cc] = (_Float16)(acc[i][j][e] + bv_);
      }
    }
  } else {
    for (int j = 0; j < 4; j++) {
      int cc = n0 + wn + j * 16 + c;
      float bv_ = bias[cc];
      int h_ = cc >> 6, dh = cc & 63;
      for (int i = 0; i < 4; i++) {
        int r = m0 + wm + i * 16 + g * 4;
        int b_ = r >> 10, key = r & 1023;
        union { uint2 u; _Float16 hh[4]; } o;
        for (int e = 0; e < 4; e++) o.hh[e] = (_Float16)(acc[i][j][e] + bv_);
        *(uint2*)&VT16[((size_t)((b_ * 16 + h_) * 64 + dh)) * 1024 + key] = o.u;
      }
    }
  }
}

// ---- output GEMM: 128x64, BK=32, triple-buffer counted vmcnt (3 loads/iter) -------------
__global__ __launch_bounds__(256, 4) void gemm_out_kernel(
    const _Float16* __restrict__ ctx16, const _Float16* __restrict__ WoT,
    const float* __restrict__ bo, float* __restrict__ out) {
  int ord = blockIdx.x + (blockIdx.y << 4);
  int wgid = (ord & 7) * 64 + (ord >> 3);
  int n0 = (wgid & 15) * 64, m0 = (wgid >> 4) * 128;
  const int K = 1024;
  __shared__ _Float16 Alds[3][128 * 32];
  __shared__ _Float16 Blds[3][64 * 32];
  int tid = threadIdx.x, lane = tid & 63, w = tid >> 6;
  int c = lane & 15, g = lane >> 4;
  int wm = (w & 1) * 64, wn = (w >> 1) * 32;
  int rr = lane >> 2;
  int su = ((lane & 3) ^ (rr & 3)) * 8;

  const _Float16* gA[2]; int laoff[2];
  for (int p = 0; p < 2; p++) {
    int row = w * 32 + p * 16 + rr;
    gA[p] = &ctx16[(size_t)(m0 + row) * K + su];
    laoff[p] = (w * 32 + p * 16) * 32;
  }
  const _Float16* gB; int lboff;
  {
    int row = w * 16 + rr;
    gB = &WoT[(size_t)(n0 + row) * K + su];
    lboff = (w * 16) * 32;
  }

  f32x4 acc[4][2];
  for (int i = 0; i < 4; i++)
    for (int j = 0; j < 2; j++)
      acc[i][j] = (f32x4){0.f, 0.f, 0.f, 0.f};

  for (int t = 0; t < 2; t++) {
    for (int p = 0; p < 2; p++) gload_lds16(gA[p] + t * 32, &Alds[t][laoff[p]]);
    gload_lds16(gB + t * 32, &Blds[t][lboff]);
  }

  int xa = (c & 3) << 4;
  int cur = 0;
  for (int kt = 0; kt < 32; kt++) {
    if (kt < 31) { asm volatile("s_waitcnt vmcnt(3)" ::: "memory"); }
    else         { asm volatile("s_waitcnt vmcnt(0)" ::: "memory"); }
    __builtin_amdgcn_s_barrier();
    __builtin_amdgcn_sched_barrier(0);
    if (kt + 2 < 32) {
      int s2 = cur + 2; if (s2 >= 3) s2 -= 3;
      for (int p = 0; p < 2; p++) gload_lds16(gA[p] + (kt + 2) * 32, &Alds[s2][laoff[p]]);
      gload_lds16(gB + (kt + 2) * 32, &Blds[s2][lboff]);
    }
    const char* ab = (const char*)&Alds[cur][0];
    const char* bb = (const char*)&Blds[cur][0];
    f16x8 af[4], bf[2];
    for (int i = 0; i < 4; i++)
      af[i] = *(const f16x8*)(ab + (wm + i * 16 + c) * 64 + ((g * 16) ^ xa));
    for (int j = 0; j < 2; j++)
      bf[j] = *(const f16x8*)(bb + (wn + j * 16 + c) * 64 + ((g * 16) ^ xa));
    for (int i = 0; i < 4; i++)
      for (int j = 0; j < 2; j++)
        acc[i][j] = __builtin_amdgcn_mfma_f32_16x16x32_f16(af[i], bf[j], acc[i][j], 0, 0, 0);
    cur = (cur == 2) ? 0 : cur + 1;
  }
  for (int j = 0; j < 2; j++) {
    float bv_ = bo[n0 + wn + j * 16 + c];
    for (int i = 0; i < 4; i++) {
      int r = m0 + wm + i * 16 + g * 4;
      int cc = n0 + wn + j * 16 + c;
      for (int e = 0; e < 4; e++)
        out[(size_t)(r + e) * 1024 + cc] = acc[i][j][e] + bv_;
    }
  }
}

// ---- flash attention: 4 waves x 32 q-rows (amortized), bitmask madd, no XCD swizzle ----
// grid (8,16,4)=512 blocks; LDS 48KB -> 3 blocks/CU.
__global__ __launch_bounds__(256, 3) void attn_kernel(
    const _Float16* __restrict__ Q16, const _Float16* __restrict__ K16,
    const _Float16* __restrict__ VT16,
    const int* __restrict__ q_mask, const u64* __restrict__ mask_bits,
    _Float16* __restrict__ ctx16) {
  int qb = blockIdx.x, h = blockIdx.y, b = blockIdx.z;
  int tid = threadIdx.x, lane = tid & 63, w = tid >> 6;
  int c = lane & 15, g = lane >> 4;
  int lr = lane >> 3, ls = lane & 7;

  __shared__ _Float16 QP[128 * 64];     // Q tile (16KB), reused as per-wave P
  __shared__ _Float16 Kl[2][64 * 64];
  __shared__ _Float16 Vl[2][64 * 64];

  const _Float16* Qg = Q16 + ((size_t)(b * 1024 + qb * 128)) * 1024 + h * 64;
  const _Float16* Kg = K16 + ((size_t)(b * 1024)) * 1024 + h * 64;
  const _Float16* Vg = VT16 + ((size_t)(b * 16 + h)) * 64 * 1024;

  int kx = (ls ^ lr) * 8;
  // Q: wave w stages its own 32 rows (chunks 4w..4w+3)
  for (int p = 0; p < 4; p++) {
    int ch = w * 4 + p;
    gload_lds16(Qg + (size_t)(ch * 8 + lr) * 1024 + kx, QP + ch * 512);
  }
  int row0 = w * 16 + lr, row1 = row0 + 8;
  int ch0 = w * 2, ch1 = ch0 + 1;
  gload_lds16(Kg + (size_t)row0 * 1024 + kx, &Kl[0][ch0 * 512]);
  gload_lds16(Kg + (size_t)row1 * 1024 + kx, &Kl[0][ch1 * 512]);
  gload_lds16(Vg + (size_t)row0 * 1024 + kx, &Vl[0][ch0 * 512]);
  gload_lds16(Vg + (size_t)row1 * 1024 + kx, &Vl[0][ch1 * 512]);
  __syncthreads();

  f16x8 qf[2][2];
  {
    const _Float16 l2e = (_Float16)1.44269504f;
    for (int i = 0; i < 2; i++) {
      int row = w * 32 + i * 16 + c;
      const char* rb = (const char*)QP + row * 128;
      int x = (c & 7) << 4;
      qf[i][0] = *(const f16x8*)(rb + ((g * 16) ^ x));
      qf[i][1] = *(const f16x8*)(rb + ((64 + g * 16) ^ x));
      for (int e = 0; e < 8; e++) { qf[i][0][e] *= l2e; qf[i][1][e] *= l2e; }
    }
  }

  float lp[2][4];
  f32x4 acc_o[2][4];
  for (int i = 0; i < 2; i++)
    for (int e = 0; e < 4; e++) lp[i][e] = 0.f;
  for (int i = 0; i < 2; i++)
    for (int jd = 0; jd < 4; jd++) acc_o[i][jd] = (f32x4){0.f, 0.f, 0.f, 0.f};

  char* pb = (char*)QP;
  int cur = 0;
  const float REF = -23.0831222f;  // -16 * log2(e)
  for (int kb = 0; kb < 16; kb++) {
    if (kb + 1 < 16) {
      int nb = cur ^ 1;
      const _Float16* kgs = Kg + (size_t)(kb + 1) * 64 * 1024;
      const _Float16* vgs = Vg + (kb + 1) * 64;
      gload_lds16(kgs + (size_t)row0 * 1024 + kx, &Kl[nb][ch0 * 512]);
      gload_lds16(kgs + (size_t)row1 * 1024 + kx, &Kl[nb][ch1 * 512]);
      gload_lds16(vgs + (size_t)row0 * 1024 + kx, &Vl[nb][ch0 * 512]);
      gload_lds16(vgs + (size_t)row1 * 1024 + kx, &Vl[nb][ch1 * 512]);
    }
    // wave-uniform 64-bit mask for this tile (s_load, no vmcnt traffic)
    u64 bits = mask_bits[b * 16 + kb];
    float madd[4];
    for (int j = 0; j < 4; j++)
      madd[j] = ((bits >> (unsigned)(j * 16 + c)) & 1ull) ? REF : -1e30f;

    // shared K frags for both q-subtiles
    f16x8 kf[4][2];
    const char* kbse = (const char*)&Kl[cur][0];
    for (int j = 0; j < 4; j++) {
      int row = j * 16 + c;
      const char* rb = kbse + row * 128;
      int x = (row & 7) << 4;
      kf[j][0] = *(const f16x8*)(rb + ((g * 16) ^ x));
      kf[j][1] = *(const f16x8*)(rb + ((64 + g * 16) ^ x));
    }

    for (int i = 0; i < 2; i++) {
      f32x4 s[4];
      for (int j = 0; j < 4; j++) {
        s[j] = (f32x4){0.f, 0.f, 0.f, 0.f};
        s[j] = __builtin_amdgcn_mfma_f32_16x16x32_f16(qf[i][0], kf[j][0], s[j], 0, 0, 0);
        s[j] = __builtin_amdgcn_mfma_f32_16x16x32_f16(qf[i][1], kf[j][1], s[j], 0, 0, 0);
      }
      for (int j = 0; j < 4; j++)
        for (int e = 0; e < 4; e++) {
          float p = exp2f(s[j][e] + madd[j]);
          s[j][e] = p;
          lp[i][e] += p;
        }
      for (int j = 0; j < 4; j++)
        for (int e = 0; e < 4; e++) {
          int prow = w * 32 + i * 16 + g * 4 + e;
          int pby = prow * 128 + (((j * 16 + c) * 2) ^ ((prow & 7) << 4));
          *(_Float16*)(pb + pby) = (_Float16)s[j][e];
        }
    }
    asm volatile("s_waitcnt lgkmcnt(0)" ::: "memory");
    __builtin_amdgcn_sched_barrier(0);

    // PV: V frags shared across both q-subtiles
    const char* vbse = (const char*)&Vl[cur][0];
    for (int ks = 0; ks < 2; ks++) {
      f16x8 vf[4];
      for (int jd = 0; jd < 4; jd++) {
        int vrow = jd * 16 + c;
        vf[jd] = *(const f16x8*)(vbse + vrow * 128 +
                                 ((ks * 64 + g * 16) ^ ((vrow & 7) << 4)));
      }
      for (int i = 0; i < 2; i++) {
        int prow = w * 32 + i * 16 + c;
        f16x8 pf = *(const f16x8*)(pb + prow * 128 +
                                   ((ks * 64 + g * 16) ^ ((c & 7) << 4)));
        for (int jd = 0; jd < 4; jd++)
          acc_o[i][jd] = __builtin_amdgcn_mfma_f32_16x16x32_f16(pf, vf[jd], acc_o[i][jd], 0, 0, 0);
      }
    }

    __syncthreads();
    cur ^= 1;
  }

  for (int i = 0; i < 2; i++)
    for (int e = 0; e < 4; e++) {
      lp[i][e] += __shfl_xor(lp[i][e], 1);
      lp[i][e] += __shfl_xor(lp[i][e], 2);
      lp[i][e] += __shfl_xor(lp[i][e], 4);
      lp[i][e] += __shfl_xor(lp[i][e], 8);
    }

  for (int i = 0; i < 2; i++) {
    int qrow = b * 1024 + qb * 128 + w * 32 + i * 16 + g * 4;
    float inv[4];
    for (int e = 0; e < 4; e++) {
      float qm = q_mask[qrow + e] ? 1.0f : 0.0f;
      inv[e] = qm / lp[i][e];
    }
    _Float16* cb = ctx16 + ((size_t)qrow) * 1024 + h * 64;
    for (int jd = 0; jd < 4; jd++)
      for (int e = 0; e < 4; e++)
        cb[(size_t)e * 1024 + jd * 16 + c] = (_Float16)(acc_o[i][jd][e] * inv[e]);
  }
}

// ---------------- launch ----------------
extern "C" void kernel_launch(void* const* d_in, const int* in_sizes, int n_in,
                              void* d_out, int out_size, void* d_ws, size_t ws_size,
                              hipStream_t stream) {
  const float* q  = (const float*)d_in[0];
  const float* v  = (const float*)d_in[1];
  const int* q_mask = (const int*)d_in[2];
  const int* v_mask = (const int*)d_in[3];
  const float* Wq = (const float*)d_in[4];
  const float* bq = (const float*)d_in[5];
  const float* Wk = (const float*)d_in[6];
  const float* bk = (const float*)d_in[7];
  const float* Wv = (const float*)d_in[8];
  const float* bv = (const float*)d_in[9];
  const float* Wo = (const float*)d_in[10];
  const float* bo = (const float*)d_in[11];
  float* out = (float*)d_out;

  _Float16* ws = (_Float16*)d_ws;
  const size_t NE = (size_t)4 * 1024 * 1024;
  _Float16* q16   = ws;
  _Float16* v16   = ws + NE;
  _Float16* Q16   = ws + 2 * NE;
  _Float16* K16   = ws + 3 * NE;
  _Float16* VT16  = ws + 4 * NE;
  _Float16* ctx16 = ws + 5 * NE;
  _Float16* WqT   = ws + 6 * NE;
  _Float16* WkT   = WqT + 1024 * 1024;
  _Float16* WvT   = WkT + 1024 * 1024;
  _Float16* WoT   = WvT + 1024 * 1024;
  u64* mask_bits  = (u64*)(WoT + 1024 * 1024);  // 64 x u64 = 512B

  prep_kernel<<<dim3(256, 21), 256, 0, stream>>>(q, v, Wq, Wk, Wv, Wo, v_mask,
                                                 q16, v16, WqT, WkT, WvT, WoT, mask_bits);
  gemm_qkv_kernel<<<dim3(8, 32, 3), 256, 0, stream>>>(q16, v16, WqT, WkT, WvT,
                                                      bq, bk, bv, Q16, K16, VT16);
  attn_kernel<<<dim3(8, 16, 4), 256, 0, stream>>>(Q16, K16, VT16, q_mask, mask_bits, ctx16);
  gemm_out_kernel<<<dim3(16, 32), 256, 0, stream>>>(ctx16, WoT, bo, out);
}